// Round 1
// baseline (63.006 us; speedup 1.0000x reference)
//
#include <hip/hip_runtime.h>
#include <hip/hip_bf16.h>

#define BATCH   16384
#define NCLS    1000
#define NPAD    1024
#define FDIM    512

typedef __bf16 bf16x8 __attribute__((ext_vector_type(8)));
typedef float  f32x16 __attribute__((ext_vector_type(16)));

#define GLOBAL_AS __attribute__((address_space(1)))
#define LDS_AS    __attribute__((address_space(3)))

// ---------------------------------------------------------------------------
// prep: centers(fp32)[1000][512] -> cb(bf16)[1024][512] (pad rows zero),
//       cnorm[c] = ||c||^2 (1e30 for pad rows, so they never win the min)
// ---------------------------------------------------------------------------
__global__ __launch_bounds__(256) void prep_centers(
    const float* __restrict__ centers, __bf16* __restrict__ cb,
    float* __restrict__ cnorm)
{
    const int c = blockIdx.x;      // 0..1023
    const int t = threadIdx.x;     // 0..255, 2 elements each
    float ssum = 0.f;
    if (c < NCLS) {
        const float2 v = *(const float2*)(centers + c * FDIM + t * 2);
        cb[c * FDIM + t * 2 + 0] = (__bf16)v.x;
        cb[c * FDIM + t * 2 + 1] = (__bf16)v.y;
        ssum = v.x * v.x + v.y * v.y;
    } else {
        cb[c * FDIM + t * 2 + 0] = (__bf16)0.f;
        cb[c * FDIM + t * 2 + 1] = (__bf16)0.f;
    }
    __shared__ float red[4];
    #pragma unroll
    for (int o = 32; o > 0; o >>= 1) ssum += __shfl_down(ssum, o);
    if ((t & 63) == 0) red[t >> 6] = ssum;
    __syncthreads();
    if (t == 0) cnorm[c] = (c < NCLS) ? (red[0] + red[1] + red[2] + red[3]) : 1e30f;
}

// ---------------------------------------------------------------------------
// main: per block, 64 rows x all 1024 classes.
//   s[c] = ||c||^2 - 2*x.c   (the ||x||^2 term cancels in dist - dist_min)
//   A (x rows, cvt to bf16) staged full-K in LDS (64KB, chunk^ (row&7) swizzle)
//   B (centers bf16) double-buffered 32KB k-slabs via global_load_lds,
//     source pre-swizzled so linear LDS dest + swizzled ds_read agree (m173).
//   Wave tile 64x64 = 2x2 frags of mfma_f32_32x32x16_bf16.
// LDS map: [0,64K) A | [64K,96K) B buf0 | [96K,128K) B buf1
// ---------------------------------------------------------------------------
__global__ __launch_bounds__(256, 1) void trip_main(
    const float* __restrict__ x, const int* __restrict__ labels,
    const __bf16* __restrict__ cb, const float* __restrict__ cnorm,
    const float* __restrict__ margin, float* __restrict__ partials)
{
    extern __shared__ char lds[];
    const int t    = threadIdx.x;
    const int lane = t & 63;
    const int w    = t >> 6;          // wave 0..3
    const int hi   = lane >> 5;       // 0/1 (k-group)
    const int l31  = lane & 31;
    const int m0   = blockIdx.x * 64;

    // ---- stage A: 64 rows x 512 k, fp32 -> bf16, swizzled ----
    {
        const int row = t >> 2, q = t & 3;   // 4 threads per row, 128 floats each
        const float* xp = x + (size_t)(m0 + row) * FDIM + q * 128;
        char* rowbase = lds + row * 1024;
        #pragma unroll
        for (int i = 0; i < 16; ++i) {
            float4 f0 = *(const float4*)(xp + i * 8);
            float4 f1 = *(const float4*)(xp + i * 8 + 4);
            bf16x8 b;
            b[0] = (__bf16)f0.x; b[1] = (__bf16)f0.y;
            b[2] = (__bf16)f0.z; b[3] = (__bf16)f0.w;
            b[4] = (__bf16)f1.x; b[5] = (__bf16)f1.y;
            b[6] = (__bf16)f1.z; b[7] = (__bf16)f1.w;
            const int chunk = q * 16 + i;                 // 16B chunk 0..63
            *(bf16x8*)(rowbase + ((chunk ^ (row & 7)) * 16)) = b;
        }
    }

    // ---- per-lane state: rows this lane owns in the D fragments ----
    int   lab [2][16];
    float minv[2][16];
    float dist[2][16];
    #pragma unroll
    for (int mi = 0; mi < 2; ++mi)
      #pragma unroll
      for (int r = 0; r < 16; ++r) {
        const int row = m0 + mi * 32 + (r & 3) + 8 * (r >> 2) + 4 * hi;
        lab[mi][r]  = labels[row];
        minv[mi][r] = 1e30f;
        dist[mi][r] = -1e30f;
      }
    const float marg = margin[0];

    // ---- B slab staging: wave w stages its 64 classes (8 x 1KB DMA) ----
    auto stageB = [&](int ct, int ko, int buf) {
        char* dst0 = lds + 64 * 1024 + buf * (32 * 1024) + (w * 64) * 128;
        const int Rl   = w * 64 + (lane >> 3);        // class-in-slab this lane serves
        const int schk = (lane & 7) ^ (lane >> 3);    // pre-swizzled source chunk
        const char* src0 = (const char*)cb
                         + (size_t)(ct * 256 + Rl) * (FDIM * 2)
                         + ko * 128 + schk * 16;
        #pragma unroll
        for (int j = 0; j < 8; ++j) {
            __builtin_amdgcn_global_load_lds(
                (const GLOBAL_AS void*)(src0 + (size_t)j * 8 * (FDIM * 2)),
                (LDS_AS void*)(dst0 + j * 1024), 16, 0, 0);
        }
    };

    stageB(0, 0, 0);

    #pragma unroll 1
    for (int ct = 0; ct < 4; ++ct) {          // 4 class-tiles of 256
        f32x16 acc[2][2];
        #pragma unroll
        for (int mi = 0; mi < 2; ++mi)
          #pragma unroll
          for (int ni = 0; ni < 2; ++ni)
            #pragma unroll
            for (int r = 0; r < 16; ++r) acc[mi][ni][r] = 0.f;

        #pragma unroll 1
        for (int ko = 0; ko < 8; ++ko) {      // K slabs of 64
            __syncthreads();                  // slab ko ready; prev buf free
            if (ko < 7)      stageB(ct, ko + 1, (ko + 1) & 1);
            else if (ct < 3) stageB(ct + 1, 0, 0);
            const char* Bb = lds + 64 * 1024 + (ko & 1) * (32 * 1024);
            #pragma unroll
            for (int ks = 0; ks < 4; ++ks) {  // 4 k-steps of 16
                const int k   = ko * 64 + ks * 16 + hi * 8;
                const int chA = k >> 3;
                bf16x8 a0 = *(const bf16x8*)(lds + (l31     ) * 1024 + ((chA ^ (l31 & 7)) * 16));
                bf16x8 a1 = *(const bf16x8*)(lds + (l31 + 32) * 1024 + ((chA ^ (l31 & 7)) * 16));
                const int chB = ks * 2 + hi;
                const int R0  = w * 64 + l31, R1 = R0 + 32;
                bf16x8 b0 = *(const bf16x8*)(Bb + R0 * 128 + ((chB ^ (R0 & 7)) * 16));
                bf16x8 b1 = *(const bf16x8*)(Bb + R1 * 128 + ((chB ^ (R1 & 7)) * 16));
                acc[0][0] = __builtin_amdgcn_mfma_f32_32x32x16_bf16(a0, b0, acc[0][0], 0, 0, 0);
                acc[0][1] = __builtin_amdgcn_mfma_f32_32x32x16_bf16(a0, b1, acc[0][1], 0, 0, 0);
                acc[1][0] = __builtin_amdgcn_mfma_f32_32x32x16_bf16(a1, b0, acc[1][0], 0, 0, 0);
                acc[1][1] = __builtin_amdgcn_mfma_f32_32x32x16_bf16(a1, b1, acc[1][1], 0, 0, 0);
            }
        }

        // ---- epilogue for this class tile: fold into running min / dist ----
        #pragma unroll
        for (int ni = 0; ni < 2; ++ni) {
            const int cls  = ct * 256 + w * 64 + ni * 32 + l31;
            const float cn = cnorm[cls];
            #pragma unroll
            for (int mi = 0; mi < 2; ++mi)
              #pragma unroll
              for (int r = 0; r < 16; ++r) {
                const float s  = cn - 2.0f * acc[mi][ni][r];
                const bool isl = (cls == lab[mi][r]);
                dist[mi][r] = isl ? s : dist[mi][r];
                minv[mi][r] = (!isl && s < minv[mi][r]) ? s : minv[mi][r];
              }
        }
    }

    // ---- reduce across the 32 class-lanes within each half-wave ----
    #pragma unroll
    for (int mi = 0; mi < 2; ++mi)
      #pragma unroll
      for (int r = 0; r < 16; ++r) {
        float mv = minv[mi][r], dv = dist[mi][r];
        #pragma unroll
        for (int o = 1; o <= 16; o <<= 1) {
            mv = fminf(mv, __shfl_xor(mv, o));
            dv = fmaxf(dv, __shfl_xor(dv, o));
        }
        minv[mi][r] = mv; dist[mi][r] = dv;
      }

    __syncthreads();                      // done with A region; reuse as scratch
    float* rmin = (float*)lds;            // [64]
    float* rdst = rmin + 64;              // [64]
    #pragma unroll 1
    for (int wv = 0; wv < 4; ++wv) {      // serialize waves into row arrays
        if (w == wv && (lane & 31) == 0) {
            #pragma unroll
            for (int mi = 0; mi < 2; ++mi)
              #pragma unroll
              for (int r = 0; r < 16; ++r) {
                const int row = mi * 32 + (r & 3) + 8 * (r >> 2) + 4 * hi;
                if (wv == 0) { rmin[row] = minv[mi][r]; rdst[row] = dist[mi][r]; }
                else {
                    rmin[row] = fminf(rmin[row], minv[mi][r]);
                    rdst[row] = fmaxf(rdst[row], dist[mi][r]);
                }
              }
        }
        __syncthreads();
    }
    if (t < 64) {
        float loss = fmaxf(marg + rdst[t] - rmin[t], 0.f);
        #pragma unroll
        for (int o = 32; o > 0; o >>= 1) loss += __shfl_down(loss, o);
        if (t == 0) partials[blockIdx.x] = loss;
    }
}

// ---------------------------------------------------------------------------
__global__ __launch_bounds__(256) void finalize(
    const float* __restrict__ partials, float* __restrict__ out)
{
    const int t = threadIdx.x;
    float s = partials[t];     // 256 partials, one per block
    __shared__ float red[4];
    #pragma unroll
    for (int o = 32; o > 0; o >>= 1) s += __shfl_down(s, o);
    if ((t & 63) == 0) red[t >> 6] = s;
    __syncthreads();
    if (t == 0) out[0] = (red[0] + red[1] + red[2] + red[3]) * (1.0f / BATCH);
}

extern "C" void kernel_launch(void* const* d_in, const int* in_sizes, int n_in,
                              void* d_out, int out_size, void* d_ws, size_t ws_size,
                              hipStream_t stream)
{
    const float* x       = (const float*)d_in[0];
    const int*   labels  = (const int*)d_in[1];
    const float* centers = (const float*)d_in[2];
    const float* margin  = (const float*)d_in[3];
    float* out = (float*)d_out;

    char* ws = (char*)d_ws;
    __bf16* cb    = (__bf16*)ws;                                  // 1 MB
    float*  cnorm = (float*)(ws + NPAD * FDIM * 2);               // 4 KB
    float*  parts = (float*)(ws + NPAD * FDIM * 2 + NPAD * 4);    // 1 KB

    (void)hipFuncSetAttribute((const void*)trip_main,
                              hipFuncAttributeMaxDynamicSharedMemorySize, 128 * 1024);

    prep_centers<<<NPAD, 256, 0, stream>>>(centers, cb, cnorm);
    trip_main<<<BATCH / 64, 256, 128 * 1024, stream>>>(x, labels, cb, cnorm, margin, parts);
    finalize<<<1, 256, 0, stream>>>(parts, out);
}

// Round 2
// 53.369 us; speedup vs baseline: 1.1806x; 1.1806x over previous
//
#include <hip/hip_runtime.h>
#include <hip/hip_bf16.h>

#define BATCH 16384
#define NCLS  1000
#define NPAD  1024
#define FDIM  512
#define KEXT  528              // 512 + 16 (cnorm fold block)
#define ROWB  1056             // KEXT * 2 bytes per cb row

typedef __bf16 bf16x8 __attribute__((ext_vector_type(8)));
typedef float  f32x16 __attribute__((ext_vector_type(16)));
typedef float  f32x4  __attribute__((ext_vector_type(4)));

#define GLOBAL_AS __attribute__((address_space(1)))
#define LDS_AS    __attribute__((address_space(3)))

#define VMCNT(n) asm volatile("s_waitcnt vmcnt(" #n ")" ::: "memory")
#define LGKM0()  asm volatile("s_waitcnt lgkmcnt(0)" ::: "memory")
#define BAR()    do { LGKM0(); __builtin_amdgcn_s_barrier(); \
                      __builtin_amdgcn_sched_barrier(0); } while (0)

// ---------------------------------------------------------------------------
// prep: centers fp32 [1000][512] -> cb bf16 [1024][528]
//   k<512: bf16(center); k=512: h=bf16(-cn/2); k=513: l=residual; rest 0.
//   pad classes (>=1000): zeros, h=-1e30 so they never win the max.
// ---------------------------------------------------------------------------
__global__ __launch_bounds__(256) void prep_centers(
    const float* __restrict__ centers, __bf16* __restrict__ cb)
{
    const int c = blockIdx.x, t = threadIdx.x;
    __bf16* row = cb + (size_t)c * KEXT;
    float ssum = 0.f;
    if (c < NCLS) {
        const float2 v = *(const float2*)(centers + (size_t)c * FDIM + t * 2);
        row[t * 2]     = (__bf16)v.x;
        row[t * 2 + 1] = (__bf16)v.y;
        ssum = v.x * v.x + v.y * v.y;
    } else {
        row[t * 2]     = (__bf16)0.f;
        row[t * 2 + 1] = (__bf16)0.f;
    }
    __shared__ float red[4];
    #pragma unroll
    for (int o = 32; o > 0; o >>= 1) ssum += __shfl_down(ssum, o);
    if ((t & 63) == 0) red[t >> 6] = ssum;
    __syncthreads();
    if (t == 0) {
        const float cn = red[0] + red[1] + red[2] + red[3];
        const float hf = (c < NCLS) ? (-0.5f * cn) : -1e30f;
        const __bf16 h = (__bf16)hf;
        const __bf16 l = (c < NCLS) ? (__bf16)(hf - (float)h) : (__bf16)0.f;
        row[512] = h; row[513] = l;
        #pragma unroll
        for (int e = 514; e < 528; ++e) row[e] = (__bf16)0.f;
    }
}

// ---------------------------------------------------------------------------
// main: classes-as-M GEMM, acc[class][batch] = dot(c,x) - cn/2  (s = -2*acc)
//  block: 256 classes x 256 batch, 8 waves (2M x 4N), wave 128x64 (4x2 frags)
//  K pipeline: BK=32, 16 slabs, depth-2 prefetch, counted vmcnt(6), raw bar.
//  A (cb bf16): global_load_lds into k-major LDS [chunk4][class256]x16B
//  B (x fp32): reg-staged, cvt to bf16, ds_write k-major [chunk4][row256]x16B
//  LDS: A 3x16K @0 | B 3x16K @48K | tailA 8K @96K | scratch 2K @104K
// ---------------------------------------------------------------------------
__global__ __launch_bounds__(512, 2) void trip_main(
    const float* __restrict__ x, const int* __restrict__ labels,
    const __bf16* __restrict__ cb, float* __restrict__ mxp,
    float* __restrict__ dap)
{
    extern __shared__ char lds[];
    const int t    = threadIdx.x;
    const int lane = t & 63;
    const int w    = t >> 6;          // 0..7
    const int wN   = w & 3, wM = w >> 2;
    const int l31  = lane & 31, hi = lane >> 5;
    const int bid  = blockIdx.x;
    const int cblk = bid & 3;         // class block 0..3
    const int bblk = bid >> 2;        // batch block 0..63
    const int class0 = cblk * 256;
    const int row0   = bblk * 256;
    const char* cbB  = (const char*)cb;

    // ---- helpers ----
    auto stageA = [&](int ko, int ai) {   // 2 instr/wave, 16KB slab
        #pragma unroll
        for (int j = 0; j < 2; ++j) {
            const int idx = w * 2 + j;
            const int chunk = idx >> 2, cgrp = idx & 3;
            const char* src = cbB + (size_t)(class0 + cgrp * 64 + lane) * ROWB
                            + ko * 64 + chunk * 16;
            char* dst = lds + ai * 16384 + chunk * 4096 + cgrp * 1024;
            __builtin_amdgcn_global_load_lds((const GLOBAL_AS void*)src,
                                             (LDS_AS void*)dst, 16, 0, 0);
        }
    };
    auto loadB = [&](int ko, f32x4* br) { // 4 dwordx4/lane
        const float* src = x + (size_t)(row0 + w * 32 + (lane >> 1)) * FDIM
                         + ko * 32 + (lane & 1) * 16;
        #pragma unroll
        for (int j = 0; j < 4; ++j) br[j] = *(const f32x4*)(src + j * 4);
    };
    auto writeB = [&](const f32x4* br, int bi) {
        const int row = w * 32 + (lane >> 1);
        char* base = lds + 49152 + bi * 16384 + row * 16;
        #pragma unroll
        for (int j = 0; j < 2; ++j) {
            bf16x8 v;
            #pragma unroll
            for (int e = 0; e < 8; ++e) v[e] = (__bf16)br[j * 2 + (e >> 2)][e & 3];
            *(bf16x8*)(base + ((lane & 1) * 2 + j) * 4096) = v;
        }
    };

    f32x16 acc[4][2];
    #pragma unroll
    for (int mi = 0; mi < 4; ++mi)
        #pragma unroll
        for (int ni = 0; ni < 2; ++ni)
            #pragma unroll
            for (int r = 0; r < 16; ++r) acc[mi][ni][r] = 0.f;

    auto compute = [&](int ai, int bi) {
        const char* A = lds + ai * 16384;
        const char* B = lds + 49152 + bi * 16384;
        #pragma unroll
        for (int ks = 0; ks < 2; ++ks) {
            const int chunk = ks * 2 + hi;
            bf16x8 a[4], b[2];
            #pragma unroll
            for (int mi = 0; mi < 4; ++mi)
                a[mi] = *(const bf16x8*)(A + chunk * 4096 + (wM * 128 + mi * 32 + l31) * 16);
            #pragma unroll
            for (int ni = 0; ni < 2; ++ni)
                b[ni] = *(const bf16x8*)(B + chunk * 4096 + (wN * 64 + ni * 32 + l31) * 16);
            #pragma unroll
            for (int mi = 0; mi < 4; ++mi)
                #pragma unroll
                for (int ni = 0; ni < 2; ++ni)
                    acc[mi][ni] = __builtin_amdgcn_mfma_f32_32x32x16_bf16(
                        a[mi], b[ni], acc[mi][ni], 0, 0, 0);
        }
    };

    // ---- prologue: labels, slabs 0&1, tail A ----
    const int lab0 = labels[row0 + wN * 64 + l31];
    const int lab1 = labels[row0 + wN * 64 + 32 + l31];

    f32x4 br0[4], br1[4];
    stageA(0, 0);
    loadB(0, br0);
    stageA(1, 1);
    loadB(1, br1);
    {   // tail A: [chunk2][class256]x16B at 96K  (1 instr/wave)
        const int chunk = w >> 2, cgrp = w & 3;
        const char* src = cbB + (size_t)(class0 + cgrp * 64 + lane) * ROWB
                        + 1024 + chunk * 16;
        char* dst = lds + 98304 + chunk * 4096 + cgrp * 1024;
        __builtin_amdgcn_global_load_lds((const GLOBAL_AS void*)src,
                                         (LDS_AS void*)dst, 16, 0, 0);
    }
    VMCNT(9);          // drain A0,B0 (labels were oldest, drained too)
    writeB(br0, 0);
    BAR();

    // ---- K pipeline: 16 slabs of 32 ----
    int cur = 0;
    #pragma unroll 1
    for (int tt = 0; tt < 16; ++tt) {
        int wr  = cur + 1; if (wr  >= 3) wr  -= 3;   // (tt+1)%3
        int pre = cur + 2; if (pre >= 3) pre -= 3;   // (tt+2)%3
        if (tt < 14) {
            stageA(tt + 2, pre);
            loadB(tt + 2, (tt & 1) ? br1 : br0);
            VMCNT(6);          // drain slab tt+1 (A DMA + B regs); keep tt+2
        } else {
            VMCNT(0);
        }
        if (tt < 15) writeB((tt & 1) ? br0 : br1, wr);
        compute(cur, cur);
        BAR();
        cur = wr;
    }

    // ---- tail k-step (k 512..527): A from tail LDS, B = (1,1,0,...) ----
    {
        const char* T = lds + 98304;
        bf16x8 bt;
        #pragma unroll
        for (int e = 0; e < 8; ++e) bt[e] = (__bf16)0.f;
        if (hi == 0) { bt[0] = (__bf16)1.0f; bt[1] = (__bf16)1.0f; }
        #pragma unroll
        for (int mi = 0; mi < 4; ++mi) {
            bf16x8 a = *(const bf16x8*)(T + hi * 4096 + (wM * 128 + mi * 32 + l31) * 16);
            #pragma unroll
            for (int ni = 0; ni < 2; ++ni)
                acc[mi][ni] = __builtin_amdgcn_mfma_f32_32x32x16_bf16(
                    a, bt, acc[mi][ni], 0, 0, 0);
        }
    }

    // ---- epilogue: per-lane max over non-label classes + label acc ----
    const int labBase = class0 + wM * 128 + hi * 4;
    const int labA0 = lab0 - labBase;
    const int labA1 = lab1 - labBase;
    float MX0 = -3e38f, MX1 = -3e38f, DA0 = -3e38f, DA1 = -3e38f;
    #pragma unroll
    for (int mi = 0; mi < 4; ++mi) {
        #pragma unroll
        for (int r = 0; r < 16; ++r) {
            const int pat = mi * 32 + (r & 3) + 8 * (r >> 2);
            {
                const float a = acc[mi][0][r];
                const bool is = (labA0 == pat);
                MX0 = fmaxf(MX0, is ? -3e38f : a);
                DA0 = is ? a : DA0;
            }
            {
                const float a = acc[mi][1][r];
                const bool is = (labA1 == pat);
                MX1 = fmaxf(MX1, is ? -3e38f : a);
                DA1 = is ? a : DA1;
            }
        }
    }
    MX0 = fmaxf(MX0, __shfl_xor(MX0, 32));
    DA0 = fmaxf(DA0, __shfl_xor(DA0, 32));
    MX1 = fmaxf(MX1, __shfl_xor(MX1, 32));
    DA1 = fmaxf(DA1, __shfl_xor(DA1, 32));

    // ---- merge the two M-waves via scratch, store partials ----
    float* sc = (float*)(lds + 104 * 1024);   // [256] MX, [256] DA
    const int i0 = (wN * 2 + 0) * 32 + l31;
    const int i1 = (wN * 2 + 1) * 32 + l31;
    if (wM == 1 && hi == 0) {
        sc[i0] = MX0; sc[256 + i0] = DA0;
        sc[i1] = MX1; sc[256 + i1] = DA1;
    }
    __syncthreads();
    if (wM == 0 && hi == 0) {
        const float M0 = fmaxf(MX0, sc[i0]),  D0 = fmaxf(DA0, sc[256 + i0]);
        const float M1 = fmaxf(MX1, sc[i1]),  D1 = fmaxf(DA1, sc[256 + i1]);
        const int rg = row0 + wN * 64 + l31;
        mxp[cblk * BATCH + rg]      = M0;
        dap[cblk * BATCH + rg]      = D0;
        mxp[cblk * BATCH + rg + 32] = M1;
        dap[cblk * BATCH + rg + 32] = D1;
    }
}

// ---------------------------------------------------------------------------
__global__ __launch_bounds__(256) void combine1(
    const float* __restrict__ mxp, const float* __restrict__ dap,
    const float* __restrict__ margin, float* __restrict__ partial)
{
    const int t = threadIdx.x;
    const int row = blockIdx.x * 256 + t;
    float mx = mxp[row];
    mx = fmaxf(mx, mxp[BATCH + row]);
    mx = fmaxf(mx, mxp[2 * BATCH + row]);
    mx = fmaxf(mx, mxp[3 * BATCH + row]);
    float da = dap[row];
    da = fmaxf(da, dap[BATCH + row]);
    da = fmaxf(da, dap[2 * BATCH + row]);
    da = fmaxf(da, dap[3 * BATCH + row]);
    // dist = -2*da, dist_min = -2*mx
    float loss = fmaxf(margin[0] - 2.f * da + 2.f * mx, 0.f);
    __shared__ float red[4];
    #pragma unroll
    for (int o = 32; o > 0; o >>= 1) loss += __shfl_down(loss, o);
    if ((t & 63) == 0) red[t >> 6] = loss;
    __syncthreads();
    if (t == 0) partial[blockIdx.x] = red[0] + red[1] + red[2] + red[3];
}

__global__ __launch_bounds__(64) void combine2(
    const float* __restrict__ partial, float* __restrict__ out)
{
    float s = partial[threadIdx.x];
    #pragma unroll
    for (int o = 32; o > 0; o >>= 1) s += __shfl_down(s, o);
    if (threadIdx.x == 0) out[0] = s * (1.0f / BATCH);
}

// ---------------------------------------------------------------------------
extern "C" void kernel_launch(void* const* d_in, const int* in_sizes, int n_in,
                              void* d_out, int out_size, void* d_ws, size_t ws_size,
                              hipStream_t stream)
{
    const float* x       = (const float*)d_in[0];
    const int*   labels  = (const int*)d_in[1];
    const float* centers = (const float*)d_in[2];
    const float* margin  = (const float*)d_in[3];
    float* out = (float*)d_out;

    char* ws = (char*)d_ws;
    __bf16* cb     = (__bf16*)ws;                          // 1,081,344 B
    float*  mxp    = (float*)(ws + 1081344);               //   262,144 B
    float*  dap    = (float*)(ws + 1343488);               //   262,144 B
    float*  part   = (float*)(ws + 1605632);               //       256 B

    (void)hipFuncSetAttribute((const void*)trip_main,
                              hipFuncAttributeMaxDynamicSharedMemorySize, 110592);

    prep_centers<<<NPAD, 256, 0, stream>>>(centers, cb);
    trip_main<<<256, 512, 110592, stream>>>(x, labels, cb, mxp, dap);
    combine1<<<64, 256, 0, stream>>>(mxp, dap, margin, part);
    combine2<<<1, 64, 0, stream>>>(part, out);
}